// Round 1
// baseline (3833.632 us; speedup 1.0000x reference)
//
#include <hip/hip_runtime.h>
#include <hip/hip_bf16.h>

#define HD 128
#define RD 64
#define H3 384

__device__ __forceinline__ float silu_f(float x) {
    return x / (1.0f + __expf(-x));
}

// s[n,h] = atom_embed[types[n], h]
__global__ void init_kernel(const int* __restrict__ types, const float* __restrict__ emb,
                            float* __restrict__ s, int N_) {
    int i = blockIdx.x * blockDim.x + threadIdx.x;
    if (i < N_ * HD) {
        int n = i >> 7;
        int k = i & 127;
        s[i] = emb[types[n] * HD + k];
    }
}

// condG[g,h] = z[g]@z_w + z_b + t_emb[g]@t_w + t_b
__global__ __launch_bounds__(128) void cond_kernel(const float* __restrict__ z, const float* __restrict__ t,
                            const float* __restrict__ z_w, const float* __restrict__ z_b,
                            const float* __restrict__ t_w, const float* __restrict__ t_b,
                            float* __restrict__ condG) {
    int g = blockIdx.x;
    int k = threadIdx.x;
    __shared__ float zr[128];
    __shared__ float te[64];
    zr[k] = z[g * 128 + k];
    if (k < 32) {
        float f = __expf(-9.2103403719761836f * (float)k / 31.0f);
        float e = t[g] * f;
        te[k] = sinf(e);
        te[32 + k] = cosf(e);
    }
    __syncthreads();
    float acc = z_b[k] + t_b[k];
    #pragma unroll 8
    for (int i = 0; i < 128; ++i) acc += zr[i] * z_w[i * 128 + k];
    #pragma unroll 8
    for (int i = 0; i < 64; ++i) acc += te[i] * t_w[i * 128 + k];
    condG[g * 128 + k] = acc;
}

// per-edge geometry: cart, dist, unit
__global__ void geom_kernel(const float* __restrict__ coords, const int* __restrict__ srcI,
                            const int* __restrict__ dstI, const int* __restrict__ batch,
                            const float* __restrict__ lattice, const float* __restrict__ offs,
                            float* __restrict__ dist, float* __restrict__ unit, int E_) {
    int e = blockIdx.x * blockDim.x + threadIdx.x;
    if (e >= E_) return;
    int sn = srcI[e], dn = dstI[e];
    float f0 = coords[dn * 3 + 0] - coords[sn * 3 + 0] + offs[e * 3 + 0];
    float f1 = coords[dn * 3 + 1] - coords[sn * 3 + 1] + offs[e * 3 + 1];
    float f2 = coords[dn * 3 + 2] - coords[sn * 3 + 2] + offs[e * 3 + 2];
    const float* Lg = lattice + batch[sn] * 9;
    float c0 = f0 * Lg[0] + f1 * Lg[3] + f2 * Lg[6];
    float c1 = f0 * Lg[1] + f1 * Lg[4] + f2 * Lg[7];
    float c2 = f0 * Lg[2] + f1 * Lg[5] + f2 * Lg[8];
    float nrm = sqrtf(c0 * c0 + c1 * c1 + c2 * c2);
    dist[e] = fmaxf(nrm, 1e-8f);
    float inv = 1.0f / fmaxf(nrm, 1e-12f);
    unit[e * 3 + 0] = c0 * inv;
    unit[e * 3 + 1] = c1 * inv;
    unit[e * 3 + 2] = c2 * inv;
}

// s[n,h] += condG[batch[n], h]
__global__ void add_cond_kernel(float* __restrict__ s, const float* __restrict__ condG,
                                const int* __restrict__ batch, int N_) {
    int i = blockIdx.x * blockDim.x + threadIdx.x;
    if (i < N_ * HD) {
        int n = i >> 7;
        s[i] += condG[batch[n] * 128 + (i & 127)];
    }
}

// phi = silu(s@w1+b1)@w2+b2   [N, 384], one block per node
__global__ __launch_bounds__(128) void phi_kernel(const float* __restrict__ s,
                           const float* __restrict__ w1, const float* __restrict__ b1,
                           const float* __restrict__ w2, const float* __restrict__ b2,
                           float* __restrict__ phi, int N_) {
    int n = blockIdx.x;
    int k = threadIdx.x;
    __shared__ float sr[128];
    __shared__ float hh[128];
    sr[k] = s[(size_t)n * 128 + k];
    __syncthreads();
    float acc = b1[k];
    #pragma unroll 8
    for (int h = 0; h < 128; ++h) acc += sr[h] * w1[h * 128 + k];
    acc = silu_f(acc);
    hh[k] = acc;
    __syncthreads();
    float p0 = b2[k], p1 = b2[128 + k], p2 = b2[256 + k];
    #pragma unroll 8
    for (int h = 0; h < 128; ++h) {
        float x = hh[h];
        p0 += x * w2[h * 384 + k];
        p1 += x * w2[h * 384 + 128 + k];
        p2 += x * w2[h * 384 + 256 + k];
    }
    size_t o = (size_t)n * 384;
    phi[o + k] = p0;
    phi[o + 128 + k] = p1;
    phi[o + 256 + k] = p2;
}

// fused edge message: filt from rbf (recomputed from dist) x rbf_w (LDS), scatter to s and dv
#define EPB 128
__global__ __launch_bounds__(512) void edge_kernel(
    const float* __restrict__ phi, const float* __restrict__ v,
    const float* __restrict__ dist, const float* __restrict__ unit,
    const int* __restrict__ srcI, const int* __restrict__ dstI,
    const float* __restrict__ rw, const float* __restrict__ rb,
    float* __restrict__ s, float* __restrict__ dv, int E_) {
    __shared__ float w_lds[RD * H3];       // 98304 B
    __shared__ float rbf_lds[4][4][RD];    // 4096 B
    for (int i = threadIdx.x; i < RD * H3; i += 512) w_lds[i] = rw[i];
    int sub = threadIdx.x >> 7;   // 0..3
    int col = threadIdx.x & 127;
    float b0 = rb[col], b1 = rb[128 + col], b2 = rb[256 + col];
    int e0 = blockIdx.x * EPB;
    int e1 = min(e0 + EPB, E_);
    for (int eb = e0; eb < e1; eb += 16) {
        __syncthreads();  // w_lds ready (iter 0); rbf_lds no longer read (iter > 0)
        {
            int r = col & 63;
            int jbase = col >> 6;  // 0 or 1
            #pragma unroll
            for (int jj = 0; jj < 2; ++jj) {
                int j = jbase + 2 * jj;
                int e = eb + sub * 4 + j;
                float val = 0.0f;
                if (e < e1) {
                    float d = dist[e];
                    float c = 6.0f * (float)r / 63.0f;
                    float tt = d - c;
                    val = __expf(-(64.0f / 6.0f) * tt * tt);
                }
                rbf_lds[sub][j][r] = val;
            }
        }
        __syncthreads();
        float f[4][3] = {};
        #pragma unroll 4
        for (int r = 0; r < 64; ++r) {
            float w0 = w_lds[r * 384 + col];
            float w1 = w_lds[r * 384 + 128 + col];
            float w2 = w_lds[r * 384 + 256 + col];
            #pragma unroll
            for (int j = 0; j < 4; ++j) {
                float rbv = rbf_lds[sub][j][r];
                f[j][0] += rbv * w0;
                f[j][1] += rbv * w1;
                f[j][2] += rbv * w2;
            }
        }
        #pragma unroll
        for (int j = 0; j < 4; ++j) {
            int e = eb + sub * 4 + j;
            if (e >= e1) continue;
            int sn = srcI[e], dn = dstI[e];
            const float* phr = phi + (size_t)sn * 384;
            const float* vr = v + (size_t)sn * 384;
            float x0 = phr[col] * (f[j][0] + b0);
            float x1 = phr[128 + col] * (f[j][1] + b1);
            float x2 = phr[256 + col] * (f[j][2] + b2);
            float u0 = unit[e * 3 + 0], u1 = unit[e * 3 + 1], u2 = unit[e * 3 + 2];
            atomicAdd(&s[(size_t)dn * 128 + col], x0);
            atomicAdd(&dv[(size_t)dn * 384 + col], x1 * vr[col] + x2 * u0);
            atomicAdd(&dv[(size_t)dn * 384 + 128 + col], x1 * vr[128 + col] + x2 * u1);
            atomicAdd(&dv[(size_t)dn * 384 + 256 + col], x1 * vr[256 + col] + x2 * u2);
        }
    }
}

// update block: one block per node
__global__ __launch_bounds__(128) void update_kernel(
    const float* __restrict__ U, const float* __restrict__ Vw,
    const float* __restrict__ w1, const float* __restrict__ b1,
    const float* __restrict__ w2, const float* __restrict__ b2,
    float* __restrict__ s, float* __restrict__ v, const float* __restrict__ dv, int N_) {
    int n = blockIdx.x;
    int k = threadIdx.x;
    __shared__ float vn[384];
    __shared__ float cat[256];
    __shared__ float a1l[128];
    size_t vo = (size_t)n * 384;
    float vnk[3];
    #pragma unroll
    for (int c = 0; c < 3; ++c) {
        float x = v[vo + c * 128 + k] + dv[vo + c * 128 + k];
        vnk[c] = x;
        vn[c * 128 + k] = x;
    }
    float sv = s[(size_t)n * 128 + k];
    __syncthreads();
    float Uv[3] = {0, 0, 0}, Vv[3] = {0, 0, 0};
    #pragma unroll 4
    for (int h = 0; h < 128; ++h) {
        float uu = U[h * 128 + k];
        float ww = Vw[h * 128 + k];
        float v0 = vn[h], v1 = vn[128 + h], v2 = vn[256 + h];
        Uv[0] += v0 * uu; Uv[1] += v1 * uu; Uv[2] += v2 * uu;
        Vv[0] += v0 * ww; Vv[1] += v1 * ww; Vv[2] += v2 * ww;
    }
    float Vn = sqrtf(Vv[0] * Vv[0] + Vv[1] * Vv[1] + Vv[2] * Vv[2] + 1e-8f);
    cat[k] = sv;
    cat[128 + k] = Vn;
    __syncthreads();
    float a1 = b1[k];
    #pragma unroll 8
    for (int j = 0; j < 256; ++j) a1 += cat[j] * w1[j * 128 + k];
    a1 = silu_f(a1);
    a1l[k] = a1;
    __syncthreads();
    float a0 = b2[k], aH = b2[128 + k], a2 = b2[256 + k];
    #pragma unroll 8
    for (int j = 0; j < 128; ++j) {
        float x = a1l[j];
        a0 += x * w2[j * 384 + k];
        aH += x * w2[j * 384 + 128 + k];
        a2 += x * w2[j * 384 + 256 + k];
    }
    float dot = 0.0f;
    #pragma unroll
    for (int c = 0; c < 3; ++c) {
        float nv = vnk[c] + a0 * Uv[c];
        v[vo + c * 128 + k] = nv;
        dot += Uv[c] * Vv[c];
    }
    s[(size_t)n * 128 + k] = sv + aH * dot + a2;
}

// output heads
__global__ __launch_bounds__(128) void heads_kernel(
    const float* __restrict__ s,
    const float* __restrict__ hc_w1, const float* __restrict__ hc_b1,
    const float* __restrict__ hc_w2, const float* __restrict__ hc_b2,
    const float* __restrict__ ht_w1, const float* __restrict__ ht_b1,
    const float* __restrict__ ht_w2, const float* __restrict__ ht_b2,
    float* __restrict__ outc, float* __restrict__ outt, int N_) {
    int n = blockIdx.x;
    int k = threadIdx.x;
    __shared__ float sr[128];
    __shared__ float h1[128];
    __shared__ float h2[128];
    sr[k] = s[(size_t)n * 128 + k];
    __syncthreads();
    float a = hc_b1[k], b = ht_b1[k];
    #pragma unroll 8
    for (int h = 0; h < 128; ++h) {
        float x = sr[h];
        a += x * hc_w1[h * 128 + k];
        b += x * ht_w1[h * 128 + k];
    }
    a = silu_f(a);
    b = silu_f(b);
    h1[k] = a;
    h2[k] = b;
    __syncthreads();
    if (k < 3) {
        float c = hc_b2[k];
        for (int j = 0; j < 128; ++j) c += h1[j] * hc_w2[j * 3 + k];
        outc[(size_t)n * 3 + k] = c;
    }
    if (k < 101) {
        float c = ht_b2[k];
        for (int j = 0; j < 128; ++j) c += h2[j] * ht_w2[j * 101 + k];
        outt[(size_t)n * 101 + k] = c;
    }
}

extern "C" void kernel_launch(void* const* d_in, const int* in_sizes, int n_in,
                              void* d_out, int out_size, void* d_ws, size_t ws_size,
                              hipStream_t stream) {
    const float* coords  = (const float*)d_in[0];
    const int*   types   = (const int*)d_in[1];
    const float* z       = (const float*)d_in[2];
    const float* t       = (const float*)d_in[3];
    const int*   eidx    = (const int*)d_in[4];
    const int*   batch   = (const int*)d_in[5];
    const float* lattice = (const float*)d_in[6];
    const float* offs    = (const float*)d_in[7];
    const float* aemb    = (const float*)d_in[8];
    const float* z_w     = (const float*)d_in[9];
    const float* z_b     = (const float*)d_in[10];
    const float* t_w     = (const float*)d_in[11];
    const float* t_b     = (const float*)d_in[12];
    const float* msg_w1  = (const float*)d_in[13];
    const float* msg_b1  = (const float*)d_in[14];
    const float* msg_w2  = (const float*)d_in[15];
    const float* msg_b2  = (const float*)d_in[16];
    const float* rbf_w   = (const float*)d_in[17];
    const float* rbf_b   = (const float*)d_in[18];
    const float* Um      = (const float*)d_in[19];
    const float* Vm      = (const float*)d_in[20];
    const float* upd_w1  = (const float*)d_in[21];
    const float* upd_b1  = (const float*)d_in[22];
    const float* upd_w2  = (const float*)d_in[23];
    const float* upd_b2  = (const float*)d_in[24];
    const float* hc_w1   = (const float*)d_in[25];
    const float* hc_b1   = (const float*)d_in[26];
    const float* hc_w2   = (const float*)d_in[27];
    const float* hc_b2   = (const float*)d_in[28];
    const float* ht_w1   = (const float*)d_in[29];
    const float* ht_b1   = (const float*)d_in[30];
    const float* ht_w2   = (const float*)d_in[31];
    const float* ht_b2   = (const float*)d_in[32];

    const int N = in_sizes[1];
    const int G = in_sizes[3];
    const int E = in_sizes[4] / 2;
    const int* srcI = eidx;
    const int* dstI = eidx + E;

    char* ws = (char*)d_ws;
    auto alloc = [&](size_t bytes) {
        char* p = ws;
        ws += (bytes + 255) & ~(size_t)255;
        return p;
    };
    float* s_buf   = (float*)alloc((size_t)N * HD * 4);
    float* v_buf   = (float*)alloc((size_t)N * H3 * 4);
    float* dv_buf  = (float*)alloc((size_t)N * H3 * 4);
    float* phi_buf = (float*)alloc((size_t)N * H3 * 4);
    float* condG   = (float*)alloc((size_t)G * HD * 4);
    float* dist    = (float*)alloc((size_t)E * 4);
    float* unit    = (float*)alloc((size_t)E * 3 * 4);

    hipMemsetAsync(v_buf, 0, (size_t)N * H3 * 4, stream);
    init_kernel<<<(N * HD + 255) / 256, 256, 0, stream>>>(types, aemb, s_buf, N);
    cond_kernel<<<G, 128, 0, stream>>>(z, t, z_w, z_b, t_w, t_b, condG);
    geom_kernel<<<(E + 255) / 256, 256, 0, stream>>>(coords, srcI, dstI, batch, lattice, offs, dist, unit, E);

    for (int l = 0; l < 4; ++l) {
        add_cond_kernel<<<(N * HD + 255) / 256, 256, 0, stream>>>(s_buf, condG, batch, N);
        phi_kernel<<<N, 128, 0, stream>>>(s_buf,
                                          msg_w1 + (size_t)l * HD * HD, msg_b1 + (size_t)l * HD,
                                          msg_w2 + (size_t)l * HD * H3, msg_b2 + (size_t)l * H3,
                                          phi_buf, N);
        hipMemsetAsync(dv_buf, 0, (size_t)N * H3 * 4, stream);
        int eblocks = (E + EPB - 1) / EPB;
        edge_kernel<<<eblocks, 512, 0, stream>>>(phi_buf, v_buf, dist, unit, srcI, dstI,
                                                 rbf_w + (size_t)l * RD * H3, rbf_b + (size_t)l * H3,
                                                 s_buf, dv_buf, E);
        update_kernel<<<N, 128, 0, stream>>>(Um + (size_t)l * HD * HD, Vm + (size_t)l * HD * HD,
                                             upd_w1 + (size_t)l * 2 * HD * HD, upd_b1 + (size_t)l * HD,
                                             upd_w2 + (size_t)l * HD * H3, upd_b2 + (size_t)l * H3,
                                             s_buf, v_buf, dv_buf, N);
    }
    heads_kernel<<<N, 128, 0, stream>>>(s_buf, hc_w1, hc_b1, hc_w2, hc_b2,
                                        ht_w1, ht_b1, ht_w2, ht_b2,
                                        (float*)d_out, (float*)d_out + (size_t)N * 3, N);
}

// Round 2
// 2324.645 us; speedup vs baseline: 1.6491x; 1.6491x over previous
//
#include <hip/hip_runtime.h>
#include <hip/hip_bf16.h>

#define HD 128
#define RD 64
#define H3 384

__device__ __forceinline__ float silu_f(float x) {
    return x / (1.0f + __expf(-x));
}

// s[n,h] = atom_embed[types[n], h]
__global__ void init_kernel(const int* __restrict__ types, const float* __restrict__ emb,
                            float* __restrict__ s, int N_) {
    int i = blockIdx.x * blockDim.x + threadIdx.x;
    if (i < N_ * HD) {
        int n = i >> 7;
        int k = i & 127;
        s[i] = emb[types[n] * HD + k];
    }
}

// condG[g,h] = z[g]@z_w + z_b + t_emb[g]@t_w + t_b
__global__ __launch_bounds__(128) void cond_kernel(const float* __restrict__ z, const float* __restrict__ t,
                            const float* __restrict__ z_w, const float* __restrict__ z_b,
                            const float* __restrict__ t_w, const float* __restrict__ t_b,
                            float* __restrict__ condG) {
    int g = blockIdx.x;
    int k = threadIdx.x;
    __shared__ float zr[128];
    __shared__ float te[64];
    zr[k] = z[g * 128 + k];
    if (k < 32) {
        float f = __expf(-9.2103403719761836f * (float)k / 31.0f);
        float e = t[g] * f;
        te[k] = sinf(e);
        te[32 + k] = cosf(e);
    }
    __syncthreads();
    float acc = z_b[k] + t_b[k];
    #pragma unroll 8
    for (int i = 0; i < 128; ++i) acc += zr[i] * z_w[i * 128 + k];
    #pragma unroll 8
    for (int i = 0; i < 64; ++i) acc += te[i] * t_w[i * 128 + k];
    condG[g * 128 + k] = acc;
}

// per-edge geometry: cart, dist, unit
__global__ void geom_kernel(const float* __restrict__ coords, const int* __restrict__ srcI,
                            const int* __restrict__ dstI, const int* __restrict__ batch,
                            const float* __restrict__ lattice, const float* __restrict__ offs,
                            float* __restrict__ dist, float* __restrict__ unit, int E_) {
    int e = blockIdx.x * blockDim.x + threadIdx.x;
    if (e >= E_) return;
    int sn = srcI[e], dn = dstI[e];
    float f0 = coords[dn * 3 + 0] - coords[sn * 3 + 0] + offs[e * 3 + 0];
    float f1 = coords[dn * 3 + 1] - coords[sn * 3 + 1] + offs[e * 3 + 1];
    float f2 = coords[dn * 3 + 2] - coords[sn * 3 + 2] + offs[e * 3 + 2];
    const float* Lg = lattice + batch[sn] * 9;
    float c0 = f0 * Lg[0] + f1 * Lg[3] + f2 * Lg[6];
    float c1 = f0 * Lg[1] + f1 * Lg[4] + f2 * Lg[7];
    float c2 = f0 * Lg[2] + f1 * Lg[5] + f2 * Lg[8];
    float nrm = sqrtf(c0 * c0 + c1 * c1 + c2 * c2);
    dist[e] = fmaxf(nrm, 1e-8f);
    float inv = 1.0f / fmaxf(nrm, 1e-12f);
    unit[e * 3 + 0] = c0 * inv;
    unit[e * 3 + 1] = c1 * inv;
    unit[e * 3 + 2] = c2 * inv;
}

// phi = silu((s+cond)@w1+b1)@w2+b2, also writes s+cond back to s.  8 nodes per block.
#define NPB 8
__global__ __launch_bounds__(128) void phi_kernel(float* __restrict__ s,
                           const float* __restrict__ condG, const int* __restrict__ batch,
                           const float* __restrict__ w1, const float* __restrict__ b1,
                           const float* __restrict__ w2, const float* __restrict__ b2,
                           float* __restrict__ phi, int N_) {
    int n0 = blockIdx.x * NPB;
    int k = threadIdx.x;
    __shared__ float sr[NPB][128];
    __shared__ float hh[NPB][128];
    #pragma unroll
    for (int j = 0; j < NPB; ++j) {
        int n = n0 + j;
        if (n < N_) {
            float x = s[(size_t)n * 128 + k] + condG[batch[n] * 128 + k];
            sr[j][k] = x;
            s[(size_t)n * 128 + k] = x;
        }
    }
    __syncthreads();
    float acc[NPB];
    #pragma unroll
    for (int j = 0; j < NPB; ++j) acc[j] = b1[k];
    #pragma unroll 4
    for (int h = 0; h < 128; ++h) {
        float wv = w1[h * 128 + k];
        #pragma unroll
        for (int j = 0; j < NPB; ++j) acc[j] += sr[j][h] * wv;
    }
    #pragma unroll
    for (int j = 0; j < NPB; ++j) hh[j][k] = silu_f(acc[j]);
    __syncthreads();
    float p0[NPB], p1[NPB], p2[NPB];
    #pragma unroll
    for (int j = 0; j < NPB; ++j) { p0[j] = b2[k]; p1[j] = b2[128 + k]; p2[j] = b2[256 + k]; }
    #pragma unroll 4
    for (int h = 0; h < 128; ++h) {
        float wa = w2[h * 384 + k];
        float wb = w2[h * 384 + 128 + k];
        float wc = w2[h * 384 + 256 + k];
        #pragma unroll
        for (int j = 0; j < NPB; ++j) {
            float x = hh[j][h];
            p0[j] += x * wa; p1[j] += x * wb; p2[j] += x * wc;
        }
    }
    #pragma unroll
    for (int j = 0; j < NPB; ++j) {
        int n = n0 + j;
        if (n < N_) {
            size_t o = (size_t)n * 384;
            phi[o + k] = p0[j];
            phi[o + 128 + k] = p1[j];
            phi[o + 256 + k] = p2[j];
        }
    }
}

// fused edge message: filt from rbf x rbf_w (bf16 in LDS), scatter to s and dv
#define EPB 128
__global__ __launch_bounds__(512) void edge_kernel(
    const float* __restrict__ phi, const float* __restrict__ v,
    const float* __restrict__ dist, const float* __restrict__ unit,
    const int* __restrict__ srcI, const int* __restrict__ dstI,
    const float* __restrict__ rw, const float* __restrict__ rb,
    float* __restrict__ s, float* __restrict__ dv, int E_) {
    __shared__ unsigned short w_lds[RD * H3];  // bf16, 49152 B
    __shared__ float rbf_lds[4][4][RD];        // 4096 B
    for (int i = threadIdx.x; i < RD * H3; i += 512) {
        __hip_bfloat16 hb = __float2bfloat16(rw[i]);
        w_lds[i] = *reinterpret_cast<unsigned short*>(&hb);
    }
    int sub = threadIdx.x >> 7;   // 0..3
    int col = threadIdx.x & 127;
    float b0 = rb[col], b1 = rb[128 + col], b2 = rb[256 + col];
    int e0 = blockIdx.x * EPB;
    int e1 = min(e0 + EPB, E_);
    for (int eb = e0; eb < e1; eb += 16) {
        __syncthreads();  // w_lds ready (iter 0); rbf_lds no longer read (iter > 0)
        {
            int r = col & 63;
            int jbase = col >> 6;  // 0 or 1
            #pragma unroll
            for (int jj = 0; jj < 2; ++jj) {
                int j = jbase + 2 * jj;
                int e = eb + sub * 4 + j;
                float val = 0.0f;
                if (e < e1) {
                    float d = dist[e];
                    float c = 6.0f * (float)r / 63.0f;
                    float tt = d - c;
                    val = __expf(-(64.0f / 6.0f) * tt * tt);
                }
                rbf_lds[sub][j][r] = val;
            }
        }
        __syncthreads();
        float f[4][3] = {};
        #pragma unroll 4
        for (int r = 0; r < 64; ++r) {
            float w0 = __uint_as_float(((unsigned)w_lds[r * 384 + col]) << 16);
            float w1 = __uint_as_float(((unsigned)w_lds[r * 384 + 128 + col]) << 16);
            float w2 = __uint_as_float(((unsigned)w_lds[r * 384 + 256 + col]) << 16);
            #pragma unroll
            for (int j = 0; j < 4; ++j) {
                float rbv = rbf_lds[sub][j][r];
                f[j][0] += rbv * w0;
                f[j][1] += rbv * w1;
                f[j][2] += rbv * w2;
            }
        }
        #pragma unroll
        for (int j = 0; j < 4; ++j) {
            int e = eb + sub * 4 + j;
            if (e >= e1) continue;
            int sn = srcI[e], dn = dstI[e];
            const float* phr = phi + (size_t)sn * 384;
            const float* vr = v + (size_t)sn * 384;
            float x0 = phr[col] * (f[j][0] + b0);
            float x1 = phr[128 + col] * (f[j][1] + b1);
            float x2 = phr[256 + col] * (f[j][2] + b2);
            float u0 = unit[e * 3 + 0], u1 = unit[e * 3 + 1], u2 = unit[e * 3 + 2];
            atomicAdd(&s[(size_t)dn * 128 + col], x0);
            atomicAdd(&dv[(size_t)dn * 384 + col], x1 * vr[col] + x2 * u0);
            atomicAdd(&dv[(size_t)dn * 384 + 128 + col], x1 * vr[128 + col] + x2 * u1);
            atomicAdd(&dv[(size_t)dn * 384 + 256 + col], x1 * vr[256 + col] + x2 * u2);
        }
    }
}

// update block: 4 nodes per block
#define UPB 4
__global__ __launch_bounds__(128) void update_kernel(
    const float* __restrict__ U, const float* __restrict__ Vw,
    const float* __restrict__ w1, const float* __restrict__ b1,
    const float* __restrict__ w2, const float* __restrict__ b2,
    float* __restrict__ s, float* __restrict__ v, const float* __restrict__ dv, int N_) {
    int n0 = blockIdx.x * UPB;
    int k = threadIdx.x;
    __shared__ float vn[UPB][384];
    __shared__ float cat[UPB][256];
    __shared__ float a1l[UPB][128];
    float vnk[UPB][3];
    float sv[UPB];
    #pragma unroll
    for (int j = 0; j < UPB; ++j) {
        int n = n0 + j;
        if (n < N_) {
            size_t vo = (size_t)n * 384;
            #pragma unroll
            for (int c = 0; c < 3; ++c) {
                float x = v[vo + c * 128 + k] + dv[vo + c * 128 + k];
                vnk[j][c] = x;
                vn[j][c * 128 + k] = x;
            }
            sv[j] = s[(size_t)n * 128 + k];
        }
    }
    __syncthreads();
    float Uv[UPB][3] = {}, Vv[UPB][3] = {};
    #pragma unroll 4
    for (int h = 0; h < 128; ++h) {
        float uu = U[h * 128 + k];
        float ww = Vw[h * 128 + k];
        #pragma unroll
        for (int j = 0; j < UPB; ++j) {
            float v0 = vn[j][h], v1 = vn[j][128 + h], v2 = vn[j][256 + h];
            Uv[j][0] += v0 * uu; Uv[j][1] += v1 * uu; Uv[j][2] += v2 * uu;
            Vv[j][0] += v0 * ww; Vv[j][1] += v1 * ww; Vv[j][2] += v2 * ww;
        }
    }
    #pragma unroll
    for (int j = 0; j < UPB; ++j) {
        float Vn = sqrtf(Vv[j][0] * Vv[j][0] + Vv[j][1] * Vv[j][1] + Vv[j][2] * Vv[j][2] + 1e-8f);
        cat[j][k] = sv[j];
        cat[j][128 + k] = Vn;
    }
    __syncthreads();
    float a1[UPB];
    #pragma unroll
    for (int j = 0; j < UPB; ++j) a1[j] = b1[k];
    #pragma unroll 4
    for (int h = 0; h < 256; ++h) {
        float wv = w1[h * 128 + k];
        #pragma unroll
        for (int j = 0; j < UPB; ++j) a1[j] += cat[j][h] * wv;
    }
    #pragma unroll
    for (int j = 0; j < UPB; ++j) a1l[j][k] = silu_f(a1[j]);
    __syncthreads();
    float a0[UPB], aH[UPB], a2[UPB];
    #pragma unroll
    for (int j = 0; j < UPB; ++j) { a0[j] = b2[k]; aH[j] = b2[128 + k]; a2[j] = b2[256 + k]; }
    #pragma unroll 4
    for (int h = 0; h < 128; ++h) {
        float wa = w2[h * 384 + k];
        float wb = w2[h * 384 + 128 + k];
        float wc = w2[h * 384 + 256 + k];
        #pragma unroll
        for (int j = 0; j < UPB; ++j) {
            float x = a1l[j][h];
            a0[j] += x * wa; aH[j] += x * wb; a2[j] += x * wc;
        }
    }
    #pragma unroll
    for (int j = 0; j < UPB; ++j) {
        int n = n0 + j;
        if (n < N_) {
            size_t vo = (size_t)n * 384;
            float dot = 0.0f;
            #pragma unroll
            for (int c = 0; c < 3; ++c) {
                float nv = vnk[j][c] + a0[j] * Uv[j][c];
                v[vo + c * 128 + k] = nv;
                dot += Uv[j][c] * Vv[j][c];
            }
            s[(size_t)n * 128 + k] = sv[j] + aH[j] * dot + a2[j];
        }
    }
}

// output heads: 8 nodes per block
__global__ __launch_bounds__(128) void heads_kernel(
    const float* __restrict__ s,
    const float* __restrict__ hc_w1, const float* __restrict__ hc_b1,
    const float* __restrict__ hc_w2, const float* __restrict__ hc_b2,
    const float* __restrict__ ht_w1, const float* __restrict__ ht_b1,
    const float* __restrict__ ht_w2, const float* __restrict__ ht_b2,
    float* __restrict__ outc, float* __restrict__ outt, int N_) {
    int n0 = blockIdx.x * NPB;
    int k = threadIdx.x;
    __shared__ float sr[NPB][128];
    __shared__ float h1[NPB][128];
    __shared__ float h2[NPB][128];
    #pragma unroll
    for (int j = 0; j < NPB; ++j) {
        int n = n0 + j;
        if (n < N_) sr[j][k] = s[(size_t)n * 128 + k];
    }
    __syncthreads();
    float a[NPB], b[NPB];
    #pragma unroll
    for (int j = 0; j < NPB; ++j) { a[j] = hc_b1[k]; b[j] = ht_b1[k]; }
    #pragma unroll 4
    for (int h = 0; h < 128; ++h) {
        float wa = hc_w1[h * 128 + k];
        float wb = ht_w1[h * 128 + k];
        #pragma unroll
        for (int j = 0; j < NPB; ++j) {
            float x = sr[j][h];
            a[j] += x * wa;
            b[j] += x * wb;
        }
    }
    #pragma unroll
    for (int j = 0; j < NPB; ++j) {
        h1[j][k] = silu_f(a[j]);
        h2[j][k] = silu_f(b[j]);
    }
    __syncthreads();
    if (k < 101) {
        for (int j = 0; j < NPB; ++j) {
            int n = n0 + j;
            if (n >= N_) break;
            float c = ht_b2[k];
            #pragma unroll 4
            for (int h = 0; h < 128; ++h) c += h2[j][h] * ht_w2[h * 101 + k];
            outt[(size_t)n * 101 + k] = c;
        }
    }
    if (k < 3) {
        for (int j = 0; j < NPB; ++j) {
            int n = n0 + j;
            if (n >= N_) break;
            float c = hc_b2[k];
            #pragma unroll 4
            for (int h = 0; h < 128; ++h) c += h1[j][h] * hc_w2[h * 3 + k];
            outc[(size_t)n * 3 + k] = c;
        }
    }
}

extern "C" void kernel_launch(void* const* d_in, const int* in_sizes, int n_in,
                              void* d_out, int out_size, void* d_ws, size_t ws_size,
                              hipStream_t stream) {
    const float* coords  = (const float*)d_in[0];
    const int*   types   = (const int*)d_in[1];
    const float* z       = (const float*)d_in[2];
    const float* t       = (const float*)d_in[3];
    const int*   eidx    = (const int*)d_in[4];
    const int*   batch   = (const int*)d_in[5];
    const float* lattice = (const float*)d_in[6];
    const float* offs    = (const float*)d_in[7];
    const float* aemb    = (const float*)d_in[8];
    const float* z_w     = (const float*)d_in[9];
    const float* z_b     = (const float*)d_in[10];
    const float* t_w     = (const float*)d_in[11];
    const float* t_b     = (const float*)d_in[12];
    const float* msg_w1  = (const float*)d_in[13];
    const float* msg_b1  = (const float*)d_in[14];
    const float* msg_w2  = (const float*)d_in[15];
    const float* msg_b2  = (const float*)d_in[16];
    const float* rbf_w   = (const float*)d_in[17];
    const float* rbf_b   = (const float*)d_in[18];
    const float* Um      = (const float*)d_in[19];
    const float* Vm      = (const float*)d_in[20];
    const float* upd_w1  = (const float*)d_in[21];
    const float* upd_b1  = (const float*)d_in[22];
    const float* upd_w2  = (const float*)d_in[23];
    const float* upd_b2  = (const float*)d_in[24];
    const float* hc_w1   = (const float*)d_in[25];
    const float* hc_b1   = (const float*)d_in[26];
    const float* hc_w2   = (const float*)d_in[27];
    const float* hc_b2   = (const float*)d_in[28];
    const float* ht_w1   = (const float*)d_in[29];
    const float* ht_b1   = (const float*)d_in[30];
    const float* ht_w2   = (const float*)d_in[31];
    const float* ht_b2   = (const float*)d_in[32];

    const int N = in_sizes[1];
    const int G = in_sizes[3];
    const int E = in_sizes[4] / 2;
    const int* srcI = eidx;
    const int* dstI = eidx + E;

    char* ws = (char*)d_ws;
    auto alloc = [&](size_t bytes) {
        char* p = ws;
        ws += (bytes + 255) & ~(size_t)255;
        return p;
    };
    float* s_buf   = (float*)alloc((size_t)N * HD * 4);
    float* v_buf   = (float*)alloc((size_t)N * H3 * 4);
    float* dv_buf  = (float*)alloc((size_t)N * H3 * 4);
    float* phi_buf = (float*)alloc((size_t)N * H3 * 4);
    float* condG   = (float*)alloc((size_t)G * HD * 4);
    float* dist    = (float*)alloc((size_t)E * 4);
    float* unit    = (float*)alloc((size_t)E * 3 * 4);

    hipMemsetAsync(v_buf, 0, (size_t)N * H3 * 4, stream);
    init_kernel<<<(N * HD + 255) / 256, 256, 0, stream>>>(types, aemb, s_buf, N);
    cond_kernel<<<G, 128, 0, stream>>>(z, t, z_w, z_b, t_w, t_b, condG);
    geom_kernel<<<(E + 255) / 256, 256, 0, stream>>>(coords, srcI, dstI, batch, lattice, offs, dist, unit, E);

    int nblocks8 = (N + NPB - 1) / NPB;
    int nblocks4 = (N + UPB - 1) / UPB;
    for (int l = 0; l < 4; ++l) {
        phi_kernel<<<nblocks8, 128, 0, stream>>>(s_buf, condG, batch,
                                          msg_w1 + (size_t)l * HD * HD, msg_b1 + (size_t)l * HD,
                                          msg_w2 + (size_t)l * HD * H3, msg_b2 + (size_t)l * H3,
                                          phi_buf, N);
        hipMemsetAsync(dv_buf, 0, (size_t)N * H3 * 4, stream);
        int eblocks = (E + EPB - 1) / EPB;
        edge_kernel<<<eblocks, 512, 0, stream>>>(phi_buf, v_buf, dist, unit, srcI, dstI,
                                                 rbf_w + (size_t)l * RD * H3, rbf_b + (size_t)l * H3,
                                                 s_buf, dv_buf, E);
        update_kernel<<<nblocks4, 128, 0, stream>>>(Um + (size_t)l * HD * HD, Vm + (size_t)l * HD * HD,
                                             upd_w1 + (size_t)l * 2 * HD * HD, upd_b1 + (size_t)l * HD,
                                             upd_w2 + (size_t)l * HD * H3, upd_b2 + (size_t)l * H3,
                                             s_buf, v_buf, dv_buf, N);
    }
    heads_kernel<<<nblocks8, 128, 0, stream>>>(s_buf, hc_w1, hc_b1, hc_w2, hc_b2,
                                        ht_w1, ht_b1, ht_w2, ht_b2,
                                        (float*)d_out, (float*)d_out + (size_t)N * 3, N);
}

// Round 3
// 2119.122 us; speedup vs baseline: 1.8091x; 1.0970x over previous
//
#include <hip/hip_runtime.h>
#include <hip/hip_bf16.h>

#define HD 128
#define RD 64
#define H3 384

__device__ __forceinline__ float silu_f(float x) {
    return x / (1.0f + __expf(-x));
}

// s[n,h] = atom_embed[types[n], h]
__global__ void init_kernel(const int* __restrict__ types, const float* __restrict__ emb,
                            float* __restrict__ s, int N_) {
    int i = blockIdx.x * blockDim.x + threadIdx.x;
    if (i < N_ * HD) {
        int n = i >> 7;
        int k = i & 127;
        s[i] = emb[types[n] * HD + k];
    }
}

// condG[g,h] = z[g]@z_w + z_b + t_emb[g]@t_w + t_b
__global__ __launch_bounds__(128) void cond_kernel(const float* __restrict__ z, const float* __restrict__ t,
                            const float* __restrict__ z_w, const float* __restrict__ z_b,
                            const float* __restrict__ t_w, const float* __restrict__ t_b,
                            float* __restrict__ condG) {
    int g = blockIdx.x;
    int k = threadIdx.x;
    __shared__ float zr[128];
    __shared__ float te[64];
    zr[k] = z[g * 128 + k];
    if (k < 32) {
        float f = __expf(-9.2103403719761836f * (float)k / 31.0f);
        float e = t[g] * f;
        te[k] = sinf(e);
        te[32 + k] = cosf(e);
    }
    __syncthreads();
    float acc = z_b[k] + t_b[k];
    #pragma unroll 8
    for (int i = 0; i < 128; ++i) acc += zr[i] * z_w[i * 128 + k];
    #pragma unroll 8
    for (int i = 0; i < 64; ++i) acc += te[i] * t_w[i * 128 + k];
    condG[g * 128 + k] = acc;
}

// per-edge geometry: cart, dist, unit (original edge order, temporary buffers)
__global__ void geom_kernel(const float* __restrict__ coords, const int* __restrict__ srcI,
                            const int* __restrict__ dstI, const int* __restrict__ batch,
                            const float* __restrict__ lattice, const float* __restrict__ offs,
                            float* __restrict__ dist, float* __restrict__ unit, int E_) {
    int e = blockIdx.x * blockDim.x + threadIdx.x;
    if (e >= E_) return;
    int sn = srcI[e], dn = dstI[e];
    float f0 = coords[dn * 3 + 0] - coords[sn * 3 + 0] + offs[e * 3 + 0];
    float f1 = coords[dn * 3 + 1] - coords[sn * 3 + 1] + offs[e * 3 + 1];
    float f2 = coords[dn * 3 + 2] - coords[sn * 3 + 2] + offs[e * 3 + 2];
    const float* Lg = lattice + batch[sn] * 9;
    float c0 = f0 * Lg[0] + f1 * Lg[3] + f2 * Lg[6];
    float c1 = f0 * Lg[1] + f1 * Lg[4] + f2 * Lg[7];
    float c2 = f0 * Lg[2] + f1 * Lg[5] + f2 * Lg[8];
    float nrm = sqrtf(c0 * c0 + c1 * c1 + c2 * c2);
    dist[e] = fmaxf(nrm, 1e-8f);
    float inv = 1.0f / fmaxf(nrm, 1e-12f);
    unit[e * 3 + 0] = c0 * inv;
    unit[e * 3 + 1] = c1 * inv;
    unit[e * 3 + 2] = c2 * inv;
}

// --- counting sort of edges by dst (edge_index is layer-invariant) ---
__global__ void hist_kernel(const int* __restrict__ dstI, int* __restrict__ cnt, int E_) {
    int e = blockIdx.x * blockDim.x + threadIdx.x;
    if (e < E_) atomicAdd(&cnt[dstI[e]], 1);
}

// exclusive prefix sum (single block Hillis-Steele over chunks)
__global__ __launch_bounds__(1024) void scan_kernel(const int* __restrict__ cnt, int* __restrict__ cur, int n) {
    __shared__ int tmp[1024];
    __shared__ int carry_s;
    if (threadIdx.x == 0) carry_s = 0;
    __syncthreads();
    for (int base = 0; base < n; base += 1024) {
        int i = base + threadIdx.x;
        int x = (i < n) ? cnt[i] : 0;
        tmp[threadIdx.x] = x;
        __syncthreads();
        for (int off = 1; off < 1024; off <<= 1) {
            int y = (threadIdx.x >= off) ? tmp[threadIdx.x - off] : 0;
            __syncthreads();
            tmp[threadIdx.x] += y;
            __syncthreads();
        }
        if (i < n) cur[i] = carry_s + tmp[threadIdx.x] - x;   // exclusive
        __syncthreads();
        if (threadIdx.x == 0) carry_s += tmp[1023];
        __syncthreads();
    }
}

// scatter edges into dst-sorted order, reordering all per-edge data
__global__ void scatter_kernel(const int* __restrict__ srcI, const int* __restrict__ dstI,
                               const float* __restrict__ dist, const float* __restrict__ unit,
                               int* __restrict__ cur,
                               float* __restrict__ dist_s, float* __restrict__ unit_s,
                               int* __restrict__ src_s, int* __restrict__ dst_s, int E_) {
    int e = blockIdx.x * blockDim.x + threadIdx.x;
    if (e >= E_) return;
    int d = dstI[e];
    int p = atomicAdd(&cur[d], 1);
    dist_s[p] = dist[e];
    unit_s[p * 3 + 0] = unit[e * 3 + 0];
    unit_s[p * 3 + 1] = unit[e * 3 + 1];
    unit_s[p * 3 + 2] = unit[e * 3 + 2];
    src_s[p] = srcI[e];
    dst_s[p] = d;
}

// phi = silu((s+cond)@w1+b1)@w2+b2, also writes s+cond back to s.  16 nodes per block.
#define NPB 16
__global__ __launch_bounds__(128) void phi_kernel(float* __restrict__ s,
                           const float* __restrict__ condG, const int* __restrict__ batch,
                           const float* __restrict__ w1, const float* __restrict__ b1,
                           const float* __restrict__ w2, const float* __restrict__ b2,
                           float* __restrict__ phi, int N_) {
    int n0 = blockIdx.x * NPB;
    int k = threadIdx.x;
    __shared__ float sr[NPB][128];
    __shared__ float hh[NPB][128];
    #pragma unroll
    for (int j = 0; j < NPB; ++j) {
        int n = n0 + j;
        if (n < N_) {
            float x = s[(size_t)n * 128 + k] + condG[batch[n] * 128 + k];
            sr[j][k] = x;
            s[(size_t)n * 128 + k] = x;
        } else sr[j][k] = 0.0f;
    }
    __syncthreads();
    float acc[NPB];
    #pragma unroll
    for (int j = 0; j < NPB; ++j) acc[j] = b1[k];
    for (int h = 0; h < 128; h += 4) {
        float wa = w1[h * 128 + k];
        float wb = w1[(h + 1) * 128 + k];
        float wc = w1[(h + 2) * 128 + k];
        float wd = w1[(h + 3) * 128 + k];
        #pragma unroll
        for (int j = 0; j < NPB; ++j) {
            const float4 x = *reinterpret_cast<const float4*>(&sr[j][h]);
            acc[j] = fmaf(x.w, wd, fmaf(x.z, wc, fmaf(x.y, wb, fmaf(x.x, wa, acc[j]))));
        }
    }
    #pragma unroll
    for (int j = 0; j < NPB; ++j) hh[j][k] = silu_f(acc[j]);
    __syncthreads();
    float p0[NPB], p1[NPB], p2[NPB];
    #pragma unroll
    for (int j = 0; j < NPB; ++j) { p0[j] = b2[k]; p1[j] = b2[128 + k]; p2[j] = b2[256 + k]; }
    for (int h = 0; h < 128; h += 2) {
        float wa0 = w2[h * 384 + k],       wa1 = w2[(h + 1) * 384 + k];
        float wb0 = w2[h * 384 + 128 + k], wb1 = w2[(h + 1) * 384 + 128 + k];
        float wc0 = w2[h * 384 + 256 + k], wc1 = w2[(h + 1) * 384 + 256 + k];
        #pragma unroll
        for (int j = 0; j < NPB; ++j) {
            const float2 x = *reinterpret_cast<const float2*>(&hh[j][h]);
            p0[j] += x.x * wa0 + x.y * wa1;
            p1[j] += x.x * wb0 + x.y * wb1;
            p2[j] += x.x * wc0 + x.y * wc1;
        }
    }
    #pragma unroll
    for (int j = 0; j < NPB; ++j) {
        int n = n0 + j;
        if (n < N_) {
            size_t o = (size_t)n * 384;
            phi[o + k] = p0[j];
            phi[o + 128 + k] = p1[j];
            phi[o + 256 + k] = p2[j];
        }
    }
}

// fused edge message on dst-sorted edges: register-segmented accumulation, flush on dst change
#define EPB 128
__global__ __launch_bounds__(512) void edge_kernel(
    const float* __restrict__ phi, const float* __restrict__ v,
    const float* __restrict__ dist_s, const float* __restrict__ unit_s,
    const int* __restrict__ src_s, const int* __restrict__ dst_s,
    const float* __restrict__ rw, const float* __restrict__ rb,
    float* __restrict__ s, float* __restrict__ dv, int E_) {
    __shared__ unsigned short w_lds[RD * H3];  // bf16, 49152 B
    __shared__ float rbf_lds[4][4][RD];        // 4096 B
    for (int i = threadIdx.x; i < RD * H3; i += 512) {
        __hip_bfloat16 hb = __float2bfloat16(rw[i]);
        w_lds[i] = *reinterpret_cast<unsigned short*>(&hb);
    }
    int sub = threadIdx.x >> 7;   // 0..3, each sub owns 32 contiguous sorted edges
    int col = threadIdx.x & 127;
    float b0 = rb[col], b1 = rb[128 + col], b2 = rb[256 + col];
    int span0 = blockIdx.x * EPB + sub * 32;
    float as = 0.0f, ad0 = 0.0f, ad1 = 0.0f, ad2 = 0.0f;
    int rd = -1;
    for (int it = 0; it < 8; ++it) {
        int eb = span0 + it * 4;
        __syncthreads();  // w_lds ready (iter 0); rbf_lds no longer read (iter > 0)
        {
            int r = col & 63;
            int jbase = col >> 6;  // 0 or 1
            #pragma unroll
            for (int jj = 0; jj < 2; ++jj) {
                int j = jbase + 2 * jj;
                int e = eb + j;
                float val = 0.0f;
                if (e < E_) {
                    float d = dist_s[e];
                    float c = 6.0f * (float)r / 63.0f;
                    float tt = d - c;
                    val = __expf(-(64.0f / 6.0f) * tt * tt);
                }
                rbf_lds[sub][j][r] = val;
            }
        }
        __syncthreads();
        float f[4][3] = {};
        #pragma unroll 4
        for (int r = 0; r < 64; ++r) {
            float w0 = __uint_as_float(((unsigned)w_lds[r * 384 + col]) << 16);
            float w1 = __uint_as_float(((unsigned)w_lds[r * 384 + 128 + col]) << 16);
            float w2 = __uint_as_float(((unsigned)w_lds[r * 384 + 256 + col]) << 16);
            #pragma unroll
            for (int j = 0; j < 4; ++j) {
                float rbv = rbf_lds[sub][j][r];
                f[j][0] += rbv * w0;
                f[j][1] += rbv * w1;
                f[j][2] += rbv * w2;
            }
        }
        #pragma unroll
        for (int j = 0; j < 4; ++j) {
            int e = eb + j;
            if (e >= E_) break;
            int dn = dst_s[e];
            if (dn != rd) {  // wave-uniform: dst uniform across the sub's lanes
                if (rd >= 0) {
                    atomicAdd(&s[(size_t)rd * 128 + col], as);
                    atomicAdd(&dv[(size_t)rd * 384 + col], ad0);
                    atomicAdd(&dv[(size_t)rd * 384 + 128 + col], ad1);
                    atomicAdd(&dv[(size_t)rd * 384 + 256 + col], ad2);
                }
                as = ad0 = ad1 = ad2 = 0.0f;
                rd = dn;
            }
            int sn = src_s[e];
            const float* phr = phi + (size_t)sn * 384;
            const float* vr = v + (size_t)sn * 384;
            float x0 = phr[col] * (f[j][0] + b0);
            float x1 = phr[128 + col] * (f[j][1] + b1);
            float x2 = phr[256 + col] * (f[j][2] + b2);
            float u0 = unit_s[e * 3 + 0], u1 = unit_s[e * 3 + 1], u2 = unit_s[e * 3 + 2];
            as += x0;
            ad0 += x1 * vr[col] + x2 * u0;
            ad1 += x1 * vr[128 + col] + x2 * u1;
            ad2 += x1 * vr[256 + col] + x2 * u2;
        }
    }
    if (rd >= 0) {
        atomicAdd(&s[(size_t)rd * 128 + col], as);
        atomicAdd(&dv[(size_t)rd * 384 + col], ad0);
        atomicAdd(&dv[(size_t)rd * 384 + 128 + col], ad1);
        atomicAdd(&dv[(size_t)rd * 384 + 256 + col], ad2);
    }
}

// update block: 8 nodes per block
#define UPB 8
__global__ __launch_bounds__(128) void update_kernel(
    const float* __restrict__ U, const float* __restrict__ Vw,
    const float* __restrict__ w1, const float* __restrict__ b1,
    const float* __restrict__ w2, const float* __restrict__ b2,
    float* __restrict__ s, float* __restrict__ v, const float* __restrict__ dv, int N_) {
    int n0 = blockIdx.x * UPB;
    int k = threadIdx.x;
    __shared__ float vn[UPB][384];
    __shared__ float cat[UPB][256];
    __shared__ float a1l[UPB][128];
    float vnk[UPB][3];
    float sv[UPB];
    #pragma unroll
    for (int j = 0; j < UPB; ++j) {
        int n = n0 + j;
        if (n < N_) {
            size_t vo = (size_t)n * 384;
            #pragma unroll
            for (int c = 0; c < 3; ++c) {
                float x = v[vo + c * 128 + k] + dv[vo + c * 128 + k];
                vnk[j][c] = x;
                vn[j][c * 128 + k] = x;
            }
            sv[j] = s[(size_t)n * 128 + k];
        } else {
            #pragma unroll
            for (int c = 0; c < 3; ++c) { vnk[j][c] = 0.0f; vn[j][c * 128 + k] = 0.0f; }
            sv[j] = 0.0f;
        }
    }
    __syncthreads();
    float Uv[UPB][3] = {}, Vv[UPB][3] = {};
    for (int h = 0; h < 128; h += 2) {
        float u0 = U[h * 128 + k],  u1 = U[(h + 1) * 128 + k];
        float w0 = Vw[h * 128 + k], w1v = Vw[(h + 1) * 128 + k];
        #pragma unroll
        for (int j = 0; j < UPB; ++j) {
            const float2 a = *reinterpret_cast<const float2*>(&vn[j][h]);
            const float2 b = *reinterpret_cast<const float2*>(&vn[j][128 + h]);
            const float2 c = *reinterpret_cast<const float2*>(&vn[j][256 + h]);
            Uv[j][0] += a.x * u0 + a.y * u1;  Vv[j][0] += a.x * w0 + a.y * w1v;
            Uv[j][1] += b.x * u0 + b.y * u1;  Vv[j][1] += b.x * w0 + b.y * w1v;
            Uv[j][2] += c.x * u0 + c.y * u1;  Vv[j][2] += c.x * w0 + c.y * w1v;
        }
    }
    #pragma unroll
    for (int j = 0; j < UPB; ++j) {
        float Vn = sqrtf(Vv[j][0] * Vv[j][0] + Vv[j][1] * Vv[j][1] + Vv[j][2] * Vv[j][2] + 1e-8f);
        cat[j][k] = sv[j];
        cat[j][128 + k] = Vn;
    }
    __syncthreads();
    float a1[UPB];
    #pragma unroll
    for (int j = 0; j < UPB; ++j) a1[j] = b1[k];
    for (int h = 0; h < 256; h += 2) {
        float wv0 = w1[h * 128 + k], wv1 = w1[(h + 1) * 128 + k];
        #pragma unroll
        for (int j = 0; j < UPB; ++j) {
            const float2 x = *reinterpret_cast<const float2*>(&cat[j][h]);
            a1[j] += x.x * wv0 + x.y * wv1;
        }
    }
    #pragma unroll
    for (int j = 0; j < UPB; ++j) a1l[j][k] = silu_f(a1[j]);
    __syncthreads();
    float a0[UPB], aH[UPB], a2[UPB];
    #pragma unroll
    for (int j = 0; j < UPB; ++j) { a0[j] = b2[k]; aH[j] = b2[128 + k]; a2[j] = b2[256 + k]; }
    for (int h = 0; h < 128; h += 2) {
        float wa0 = w2[h * 384 + k],       wa1 = w2[(h + 1) * 384 + k];
        float wb0 = w2[h * 384 + 128 + k], wb1 = w2[(h + 1) * 384 + 128 + k];
        float wc0 = w2[h * 384 + 256 + k], wc1 = w2[(h + 1) * 384 + 256 + k];
        #pragma unroll
        for (int j = 0; j < UPB; ++j) {
            const float2 x = *reinterpret_cast<const float2*>(&a1l[j][h]);
            a0[j] += x.x * wa0 + x.y * wa1;
            aH[j] += x.x * wb0 + x.y * wb1;
            a2[j] += x.x * wc0 + x.y * wc1;
        }
    }
    #pragma unroll
    for (int j = 0; j < UPB; ++j) {
        int n = n0 + j;
        if (n < N_) {
            size_t vo = (size_t)n * 384;
            float dot = 0.0f;
            #pragma unroll
            for (int c = 0; c < 3; ++c) {
                float nv = vnk[j][c] + a0[j] * Uv[j][c];
                v[vo + c * 128 + k] = nv;
                dot += Uv[j][c] * Vv[j][c];
            }
            s[(size_t)n * 128 + k] = sv[j] + aH[j] * dot + a2[j];
        }
    }
}

// output heads: 8 nodes per block
#define HPB 8
__global__ __launch_bounds__(128) void heads_kernel(
    const float* __restrict__ s,
    const float* __restrict__ hc_w1, const float* __restrict__ hc_b1,
    const float* __restrict__ hc_w2, const float* __restrict__ hc_b2,
    const float* __restrict__ ht_w1, const float* __restrict__ ht_b1,
    const float* __restrict__ ht_w2, const float* __restrict__ ht_b2,
    float* __restrict__ outc, float* __restrict__ outt, int N_) {
    int n0 = blockIdx.x * HPB;
    int k = threadIdx.x;
    __shared__ float sr[HPB][128];
    __shared__ float h1[HPB][128];
    __shared__ float h2[HPB][128];
    #pragma unroll
    for (int j = 0; j < HPB; ++j) {
        int n = n0 + j;
        if (n < N_) sr[j][k] = s[(size_t)n * 128 + k];
        else sr[j][k] = 0.0f;
    }
    __syncthreads();
    float a[HPB], b[HPB];
    #pragma unroll
    for (int j = 0; j < HPB; ++j) { a[j] = hc_b1[k]; b[j] = ht_b1[k]; }
    for (int h = 0; h < 128; h += 2) {
        float wa0 = hc_w1[h * 128 + k], wa1 = hc_w1[(h + 1) * 128 + k];
        float wb0 = ht_w1[h * 128 + k], wb1 = ht_w1[(h + 1) * 128 + k];
        #pragma unroll
        for (int j = 0; j < HPB; ++j) {
            const float2 x = *reinterpret_cast<const float2*>(&sr[j][h]);
            a[j] += x.x * wa0 + x.y * wa1;
            b[j] += x.x * wb0 + x.y * wb1;
        }
    }
    #pragma unroll
    for (int j = 0; j < HPB; ++j) {
        h1[j][k] = silu_f(a[j]);
        h2[j][k] = silu_f(b[j]);
    }
    __syncthreads();
    if (k < 101) {
        for (int j = 0; j < HPB; ++j) {
            int n = n0 + j;
            if (n >= N_) break;
            float c = ht_b2[k];
            #pragma unroll 4
            for (int h = 0; h < 128; ++h) c += h2[j][h] * ht_w2[h * 101 + k];
            outt[(size_t)n * 101 + k] = c;
        }
    }
    if (k < 3) {
        for (int j = 0; j < HPB; ++j) {
            int n = n0 + j;
            if (n >= N_) break;
            float c = hc_b2[k];
            #pragma unroll 4
            for (int h = 0; h < 128; ++h) c += h1[j][h] * hc_w2[h * 3 + k];
            outc[(size_t)n * 3 + k] = c;
        }
    }
}

extern "C" void kernel_launch(void* const* d_in, const int* in_sizes, int n_in,
                              void* d_out, int out_size, void* d_ws, size_t ws_size,
                              hipStream_t stream) {
    const float* coords  = (const float*)d_in[0];
    const int*   types   = (const int*)d_in[1];
    const float* z       = (const float*)d_in[2];
    const float* t       = (const float*)d_in[3];
    const int*   eidx    = (const int*)d_in[4];
    const int*   batch   = (const int*)d_in[5];
    const float* lattice = (const float*)d_in[6];
    const float* offs    = (const float*)d_in[7];
    const float* aemb    = (const float*)d_in[8];
    const float* z_w     = (const float*)d_in[9];
    const float* z_b     = (const float*)d_in[10];
    const float* t_w     = (const float*)d_in[11];
    const float* t_b     = (const float*)d_in[12];
    const float* msg_w1  = (const float*)d_in[13];
    const float* msg_b1  = (const float*)d_in[14];
    const float* msg_w2  = (const float*)d_in[15];
    const float* msg_b2  = (const float*)d_in[16];
    const float* rbf_w   = (const float*)d_in[17];
    const float* rbf_b   = (const float*)d_in[18];
    const float* Um      = (const float*)d_in[19];
    const float* Vm      = (const float*)d_in[20];
    const float* upd_w1  = (const float*)d_in[21];
    const float* upd_b1  = (const float*)d_in[22];
    const float* upd_w2  = (const float*)d_in[23];
    const float* upd_b2  = (const float*)d_in[24];
    const float* hc_w1   = (const float*)d_in[25];
    const float* hc_b1   = (const float*)d_in[26];
    const float* hc_w2   = (const float*)d_in[27];
    const float* hc_b2   = (const float*)d_in[28];
    const float* ht_w1   = (const float*)d_in[29];
    const float* ht_b1   = (const float*)d_in[30];
    const float* ht_w2   = (const float*)d_in[31];
    const float* ht_b2   = (const float*)d_in[32];

    const int N = in_sizes[1];
    const int G = in_sizes[3];
    const int E = in_sizes[4] / 2;
    const int* srcI = eidx;
    const int* dstI = eidx + E;

    char* ws = (char*)d_ws;
    auto alloc = [&](size_t bytes) {
        char* p = ws;
        ws += (bytes + 255) & ~(size_t)255;
        return p;
    };
    float* s_buf   = (float*)alloc((size_t)N * HD * 4);
    float* v_buf   = (float*)alloc((size_t)N * H3 * 4);
    float* dv_buf  = (float*)alloc((size_t)N * H3 * 4);
    float* phi_buf = (float*)alloc((size_t)N * H3 * 4);
    float* condG   = (float*)alloc((size_t)G * HD * 4);
    float* dist_s  = (float*)alloc((size_t)E * 4);
    float* unit_s  = (float*)alloc((size_t)E * 3 * 4);
    int*   src_s   = (int*)alloc((size_t)E * 4);
    int*   dst_s   = (int*)alloc((size_t)E * 4);
    int*   cur     = (int*)alloc((size_t)N * 4);
    // temporaries (original-order geometry) aliased into phi_buf (not yet live)
    float* dist_t  = phi_buf;                 // E floats
    float* unit_t  = phi_buf + E;             // 3E floats   (4E*4 = 2.56 MB << 30.7 MB)

    hipMemsetAsync(v_buf, 0, (size_t)N * H3 * 4, stream);
    hipMemsetAsync(cur, 0, (size_t)N * 4, stream);
    init_kernel<<<(N * HD + 255) / 256, 256, 0, stream>>>(types, aemb, s_buf, N);
    cond_kernel<<<G, 128, 0, stream>>>(z, t, z_w, z_b, t_w, t_b, condG);
    geom_kernel<<<(E + 255) / 256, 256, 0, stream>>>(coords, srcI, dstI, batch, lattice, offs, dist_t, unit_t, E);
    // counting sort by dst (reused across all 4 layers)
    hist_kernel<<<(E + 255) / 256, 256, 0, stream>>>(dstI, cur, E);
    {
        // scan needs cnt and cursor; reuse: scan reads cur (counts) and writes exclusive
        // prefix in place is unsafe -> use a second buffer inside phi_buf space
        int* cnt2 = (int*)(phi_buf + 4 * (size_t)E);  // after dist_t/unit_t region
        hipMemcpyAsync(cnt2, cur, (size_t)N * 4, hipMemcpyDeviceToDevice, stream);
        scan_kernel<<<1, 1024, 0, stream>>>(cnt2, cur, N);
    }
    scatter_kernel<<<(E + 255) / 256, 256, 0, stream>>>(srcI, dstI, dist_t, unit_t, cur,
                                                        dist_s, unit_s, src_s, dst_s, E);

    int nblocksP = (N + NPB - 1) / NPB;
    int nblocksU = (N + UPB - 1) / UPB;
    int nblocksH = (N + HPB - 1) / HPB;
    int eblocks = (E + EPB - 1) / EPB;
    for (int l = 0; l < 4; ++l) {
        phi_kernel<<<nblocksP, 128, 0, stream>>>(s_buf, condG, batch,
                                          msg_w1 + (size_t)l * HD * HD, msg_b1 + (size_t)l * HD,
                                          msg_w2 + (size_t)l * HD * H3, msg_b2 + (size_t)l * H3,
                                          phi_buf, N);
        hipMemsetAsync(dv_buf, 0, (size_t)N * H3 * 4, stream);
        edge_kernel<<<eblocks, 512, 0, stream>>>(phi_buf, v_buf, dist_s, unit_s, src_s, dst_s,
                                                 rbf_w + (size_t)l * RD * H3, rbf_b + (size_t)l * H3,
                                                 s_buf, dv_buf, E);
        update_kernel<<<nblocksU, 128, 0, stream>>>(Um + (size_t)l * HD * HD, Vm + (size_t)l * HD * HD,
                                             upd_w1 + (size_t)l * 2 * HD * HD, upd_b1 + (size_t)l * HD,
                                             upd_w2 + (size_t)l * HD * H3, upd_b2 + (size_t)l * H3,
                                             s_buf, v_buf, dv_buf, N);
    }
    heads_kernel<<<nblocksH, 128, 0, stream>>>(s_buf, hc_w1, hc_b1, hc_w2, hc_b2,
                                        ht_w1, ht_b1, ht_w2, ht_b2,
                                        (float*)d_out, (float*)d_out + (size_t)N * 3, N);
}

// Round 4
// 1823.455 us; speedup vs baseline: 2.1024x; 1.1621x over previous
//
#include <hip/hip_runtime.h>
#include <hip/hip_bf16.h>

#define HD 128
#define RD 64
#define H3 384

__device__ __forceinline__ float silu_f(float x) {
    return x / (1.0f + __expf(-x));
}

// s[n,h] = atom_embed[types[n], h]
__global__ void init_kernel(const int* __restrict__ types, const float* __restrict__ emb,
                            float* __restrict__ s, int N_) {
    int i = blockIdx.x * blockDim.x + threadIdx.x;
    if (i < N_ * HD) {
        int n = i >> 7;
        int k = i & 127;
        s[i] = emb[types[n] * HD + k];
    }
}

// condG[g,h] = z[g]@z_w + z_b + t_emb[g]@t_w + t_b
__global__ __launch_bounds__(128) void cond_kernel(const float* __restrict__ z, const float* __restrict__ t,
                            const float* __restrict__ z_w, const float* __restrict__ z_b,
                            const float* __restrict__ t_w, const float* __restrict__ t_b,
                            float* __restrict__ condG) {
    int g = blockIdx.x;
    int k = threadIdx.x;
    __shared__ float zr[128];
    __shared__ float te[64];
    zr[k] = z[g * 128 + k];
    if (k < 32) {
        float f = __expf(-9.2103403719761836f * (float)k / 31.0f);
        float e = t[g] * f;
        te[k] = sinf(e);
        te[32 + k] = cosf(e);
    }
    __syncthreads();
    float acc = z_b[k] + t_b[k];
    #pragma unroll 8
    for (int i = 0; i < 128; ++i) acc += zr[i] * z_w[i * 128 + k];
    #pragma unroll 8
    for (int i = 0; i < 64; ++i) acc += te[i] * t_w[i * 128 + k];
    condG[g * 128 + k] = acc;
}

// per-edge geometry: cart, dist, unit (original edge order, temporary buffers)
__global__ void geom_kernel(const float* __restrict__ coords, const int* __restrict__ srcI,
                            const int* __restrict__ dstI, const int* __restrict__ batch,
                            const float* __restrict__ lattice, const float* __restrict__ offs,
                            float* __restrict__ dist, float* __restrict__ unit, int E_) {
    int e = blockIdx.x * blockDim.x + threadIdx.x;
    if (e >= E_) return;
    int sn = srcI[e], dn = dstI[e];
    float f0 = coords[dn * 3 + 0] - coords[sn * 3 + 0] + offs[e * 3 + 0];
    float f1 = coords[dn * 3 + 1] - coords[sn * 3 + 1] + offs[e * 3 + 1];
    float f2 = coords[dn * 3 + 2] - coords[sn * 3 + 2] + offs[e * 3 + 2];
    const float* Lg = lattice + batch[sn] * 9;
    float c0 = f0 * Lg[0] + f1 * Lg[3] + f2 * Lg[6];
    float c1 = f0 * Lg[1] + f1 * Lg[4] + f2 * Lg[7];
    float c2 = f0 * Lg[2] + f1 * Lg[5] + f2 * Lg[8];
    float nrm = sqrtf(c0 * c0 + c1 * c1 + c2 * c2);
    dist[e] = fmaxf(nrm, 1e-8f);
    float inv = 1.0f / fmaxf(nrm, 1e-12f);
    unit[e * 3 + 0] = c0 * inv;
    unit[e * 3 + 1] = c1 * inv;
    unit[e * 3 + 2] = c2 * inv;
}

// --- counting sort of edges by dst (edge_index is layer-invariant) ---
__global__ void hist_kernel(const int* __restrict__ dstI, int* __restrict__ cnt, int E_) {
    int e = blockIdx.x * blockDim.x + threadIdx.x;
    if (e < E_) atomicAdd(&cnt[dstI[e]], 1);
}

// exclusive prefix sum (single block Hillis-Steele over chunks)
__global__ __launch_bounds__(1024) void scan_kernel(const int* __restrict__ cnt, int* __restrict__ cur, int n) {
    __shared__ int tmp[1024];
    __shared__ int carry_s;
    if (threadIdx.x == 0) carry_s = 0;
    __syncthreads();
    for (int base = 0; base < n; base += 1024) {
        int i = base + threadIdx.x;
        int x = (i < n) ? cnt[i] : 0;
        tmp[threadIdx.x] = x;
        __syncthreads();
        for (int off = 1; off < 1024; off <<= 1) {
            int y = (threadIdx.x >= off) ? tmp[threadIdx.x - off] : 0;
            __syncthreads();
            tmp[threadIdx.x] += y;
            __syncthreads();
        }
        if (i < n) cur[i] = carry_s + tmp[threadIdx.x] - x;   // exclusive
        __syncthreads();
        if (threadIdx.x == 0) carry_s += tmp[1023];
        __syncthreads();
    }
}

// scatter edges into dst-sorted order, reordering all per-edge data
__global__ void scatter_kernel(const int* __restrict__ srcI, const int* __restrict__ dstI,
                               const float* __restrict__ dist, const float* __restrict__ unit,
                               int* __restrict__ cur,
                               float* __restrict__ dist_s, float* __restrict__ unit_s,
                               int* __restrict__ src_s, int* __restrict__ dst_s, int E_) {
    int e = blockIdx.x * blockDim.x + threadIdx.x;
    if (e >= E_) return;
    int d = dstI[e];
    int p = atomicAdd(&cur[d], 1);
    dist_s[p] = dist[e];
    unit_s[p * 3 + 0] = unit[e * 3 + 0];
    unit_s[p * 3 + 1] = unit[e * 3 + 1];
    unit_s[p * 3 + 2] = unit[e * 3 + 2];
    src_s[p] = srcI[e];
    dst_s[p] = d;
}

// phi = silu((s+cond)@w1+b1)@w2+b2, also writes s+cond back to s.  16 nodes per block.
// hh aliased onto sr (sr dead after GEMM1).
#define NPB 16
__global__ __launch_bounds__(128, 4) void phi_kernel(float* __restrict__ s,
                           const float* __restrict__ condG, const int* __restrict__ batch,
                           const float* __restrict__ w1, const float* __restrict__ b1,
                           const float* __restrict__ w2, const float* __restrict__ b2,
                           float* __restrict__ phi, int N_) {
    int n0 = blockIdx.x * NPB;
    int k = threadIdx.x;
    __shared__ float sr[NPB][128];      // also serves as hh
    #pragma unroll
    for (int j = 0; j < NPB; ++j) {
        int n = n0 + j;
        if (n < N_) {
            float x = s[(size_t)n * 128 + k] + condG[batch[n] * 128 + k];
            sr[j][k] = x;
            s[(size_t)n * 128 + k] = x;
        } else sr[j][k] = 0.0f;
    }
    __syncthreads();
    float acc[NPB];
    #pragma unroll
    for (int j = 0; j < NPB; ++j) acc[j] = b1[k];
    for (int h = 0; h < 128; h += 4) {
        float wa = w1[h * 128 + k];
        float wb = w1[(h + 1) * 128 + k];
        float wc = w1[(h + 2) * 128 + k];
        float wd = w1[(h + 3) * 128 + k];
        #pragma unroll
        for (int j = 0; j < NPB; ++j) {
            const float4 x = *reinterpret_cast<const float4*>(&sr[j][h]);
            acc[j] = fmaf(x.w, wd, fmaf(x.z, wc, fmaf(x.y, wb, fmaf(x.x, wa, acc[j]))));
        }
    }
    __syncthreads();   // all sr reads done before overwrite
    #pragma unroll
    for (int j = 0; j < NPB; ++j) sr[j][k] = silu_f(acc[j]);   // hh
    __syncthreads();
    float p0[NPB], p1[NPB], p2[NPB];
    #pragma unroll
    for (int j = 0; j < NPB; ++j) { p0[j] = b2[k]; p1[j] = b2[128 + k]; p2[j] = b2[256 + k]; }
    for (int h = 0; h < 128; h += 4) {
        float wa0 = w2[h * 384 + k],       wa1 = w2[(h + 1) * 384 + k];
        float wa2 = w2[(h + 2) * 384 + k], wa3 = w2[(h + 3) * 384 + k];
        float wb0 = w2[h * 384 + 128 + k],       wb1 = w2[(h + 1) * 384 + 128 + k];
        float wb2 = w2[(h + 2) * 384 + 128 + k], wb3 = w2[(h + 3) * 384 + 128 + k];
        float wc0 = w2[h * 384 + 256 + k],       wc1 = w2[(h + 1) * 384 + 256 + k];
        float wc2 = w2[(h + 2) * 384 + 256 + k], wc3 = w2[(h + 3) * 384 + 256 + k];
        #pragma unroll
        for (int j = 0; j < NPB; ++j) {
            const float4 x = *reinterpret_cast<const float4*>(&sr[j][h]);
            p0[j] = fmaf(x.w, wa3, fmaf(x.z, wa2, fmaf(x.y, wa1, fmaf(x.x, wa0, p0[j]))));
            p1[j] = fmaf(x.w, wb3, fmaf(x.z, wb2, fmaf(x.y, wb1, fmaf(x.x, wb0, p1[j]))));
            p2[j] = fmaf(x.w, wc3, fmaf(x.z, wc2, fmaf(x.y, wc1, fmaf(x.x, wc0, p2[j]))));
        }
    }
    #pragma unroll
    for (int j = 0; j < NPB; ++j) {
        int n = n0 + j;
        if (n < N_) {
            size_t o = (size_t)n * 384;
            phi[o + k] = p0[j];
            phi[o + 128 + k] = p1[j];
            phi[o + 256 + k] = p2[j];
        }
    }
}

// fused edge message on dst-sorted edges: register-segmented accumulation, flush on dst change
#define EPB 128
__global__ __launch_bounds__(512) void edge_kernel(
    const float* __restrict__ phi, const float* __restrict__ v,
    const float* __restrict__ dist_s, const float* __restrict__ unit_s,
    const int* __restrict__ src_s, const int* __restrict__ dst_s,
    const float* __restrict__ rw, const float* __restrict__ rb,
    float* __restrict__ s, float* __restrict__ dv, int E_) {
    __shared__ unsigned short w_lds[RD * H3];  // bf16, 49152 B
    __shared__ float rbf_lds[4][4][RD];        // 4096 B
    for (int i = threadIdx.x; i < RD * H3; i += 512) {
        __hip_bfloat16 hb = __float2bfloat16(rw[i]);
        w_lds[i] = *reinterpret_cast<unsigned short*>(&hb);
    }
    int sub = threadIdx.x >> 7;   // 0..3, each sub owns 32 contiguous sorted edges
    int col = threadIdx.x & 127;
    float b0 = rb[col], b1 = rb[128 + col], b2 = rb[256 + col];
    int span0 = blockIdx.x * EPB + sub * 32;
    float as = 0.0f, ad0 = 0.0f, ad1 = 0.0f, ad2 = 0.0f;
    int rd = -1;
    for (int it = 0; it < 8; ++it) {
        int eb = span0 + it * 4;
        __syncthreads();  // w_lds ready (iter 0); rbf_lds no longer read (iter > 0)
        {
            int r = col & 63;
            int jbase = col >> 6;  // 0 or 1
            #pragma unroll
            for (int jj = 0; jj < 2; ++jj) {
                int j = jbase + 2 * jj;
                int e = eb + j;
                float val = 0.0f;
                if (e < E_) {
                    float d = dist_s[e];
                    float c = 6.0f * (float)r / 63.0f;
                    float tt = d - c;
                    val = __expf(-(64.0f / 6.0f) * tt * tt);
                }
                rbf_lds[sub][j][r] = val;
            }
        }
        __syncthreads();
        float f[4][3] = {};
        #pragma unroll 4
        for (int r = 0; r < 64; ++r) {
            float w0 = __uint_as_float(((unsigned)w_lds[r * 384 + col]) << 16);
            float w1 = __uint_as_float(((unsigned)w_lds[r * 384 + 128 + col]) << 16);
            float w2 = __uint_as_float(((unsigned)w_lds[r * 384 + 256 + col]) << 16);
            #pragma unroll
            for (int j = 0; j < 4; ++j) {
                float rbv = rbf_lds[sub][j][r];
                f[j][0] += rbv * w0;
                f[j][1] += rbv * w1;
                f[j][2] += rbv * w2;
            }
        }
        #pragma unroll
        for (int j = 0; j < 4; ++j) {
            int e = eb + j;
            if (e >= E_) break;
            int dn = dst_s[e];
            if (dn != rd) {  // wave-uniform: dst uniform across the sub's lanes
                if (rd >= 0) {
                    atomicAdd(&s[(size_t)rd * 128 + col], as);
                    atomicAdd(&dv[(size_t)rd * 384 + col], ad0);
                    atomicAdd(&dv[(size_t)rd * 384 + 128 + col], ad1);
                    atomicAdd(&dv[(size_t)rd * 384 + 256 + col], ad2);
                }
                as = ad0 = ad1 = ad2 = 0.0f;
                rd = dn;
            }
            int sn = src_s[e];
            const float* phr = phi + (size_t)sn * 384;
            const float* vr = v + (size_t)sn * 384;
            float x0 = phr[col] * (f[j][0] + b0);
            float x1 = phr[128 + col] * (f[j][1] + b1);
            float x2 = phr[256 + col] * (f[j][2] + b2);
            float u0 = unit_s[e * 3 + 0], u1 = unit_s[e * 3 + 1], u2 = unit_s[e * 3 + 2];
            as += x0;
            ad0 += x1 * vr[col] + x2 * u0;
            ad1 += x1 * vr[128 + col] + x2 * u1;
            ad2 += x1 * vr[256 + col] + x2 * u2;
        }
    }
    if (rd >= 0) {
        atomicAdd(&s[(size_t)rd * 128 + col], as);
        atomicAdd(&dv[(size_t)rd * 384 + col], ad0);
        atomicAdd(&dv[(size_t)rd * 384 + 128 + col], ad1);
        atomicAdd(&dv[(size_t)rd * 384 + 256 + col], ad2);
    }
}

// update block: 8 nodes per block, aliased LDS (vn reused for cat+a1l)
#define UPB 8
__global__ __launch_bounds__(128, 4) void update_kernel(
    const float* __restrict__ U, const float* __restrict__ Vw,
    const float* __restrict__ w1, const float* __restrict__ b1,
    const float* __restrict__ w2, const float* __restrict__ b2,
    float* __restrict__ s, float* __restrict__ v, const float* __restrict__ dv, int N_) {
    int n0 = blockIdx.x * UPB;
    int k = threadIdx.x;
    __shared__ float smem[UPB * 384];        // 12288 B: vn, later cat(UPB*256)+a1l(UPB*128)
    float* vn  = smem;
    float* cat = smem;
    float* a1l = smem + UPB * 256;
    float vnk[UPB][3];
    float sv[UPB];
    #pragma unroll
    for (int j = 0; j < UPB; ++j) {
        int n = n0 + j;
        if (n < N_) {
            size_t vo = (size_t)n * 384;
            #pragma unroll
            for (int c = 0; c < 3; ++c) {
                float x = v[vo + c * 128 + k] + dv[vo + c * 128 + k];
                vnk[j][c] = x;
                vn[j * 384 + c * 128 + k] = x;
            }
            sv[j] = s[(size_t)n * 128 + k];
        } else {
            #pragma unroll
            for (int c = 0; c < 3; ++c) { vnk[j][c] = 0.0f; vn[j * 384 + c * 128 + k] = 0.0f; }
            sv[j] = 0.0f;
        }
    }
    __syncthreads();
    float Uv[UPB][3] = {}, Vv[UPB][3] = {};
    for (int h = 0; h < 128; h += 4) {
        float u0 = U[h * 128 + k],       u1 = U[(h + 1) * 128 + k];
        float u2 = U[(h + 2) * 128 + k], u3 = U[(h + 3) * 128 + k];
        float q0 = Vw[h * 128 + k],       q1 = Vw[(h + 1) * 128 + k];
        float q2 = Vw[(h + 2) * 128 + k], q3 = Vw[(h + 3) * 128 + k];
        #pragma unroll
        for (int j = 0; j < UPB; ++j) {
            const float4 a = *reinterpret_cast<const float4*>(&vn[j * 384 + h]);
            const float4 b = *reinterpret_cast<const float4*>(&vn[j * 384 + 128 + h]);
            const float4 c = *reinterpret_cast<const float4*>(&vn[j * 384 + 256 + h]);
            Uv[j][0] = fmaf(a.w, u3, fmaf(a.z, u2, fmaf(a.y, u1, fmaf(a.x, u0, Uv[j][0]))));
            Uv[j][1] = fmaf(b.w, u3, fmaf(b.z, u2, fmaf(b.y, u1, fmaf(b.x, u0, Uv[j][1]))));
            Uv[j][2] = fmaf(c.w, u3, fmaf(c.z, u2, fmaf(c.y, u1, fmaf(c.x, u0, Uv[j][2]))));
            Vv[j][0] = fmaf(a.w, q3, fmaf(a.z, q2, fmaf(a.y, q1, fmaf(a.x, q0, Vv[j][0]))));
            Vv[j][1] = fmaf(b.w, q3, fmaf(b.z, q2, fmaf(b.y, q1, fmaf(b.x, q0, Vv[j][1]))));
            Vv[j][2] = fmaf(c.w, q3, fmaf(c.z, q2, fmaf(c.y, q1, fmaf(c.x, q0, Vv[j][2]))));
        }
    }
    __syncthreads();   // vn dead from here
    #pragma unroll
    for (int j = 0; j < UPB; ++j) {
        float Vn = sqrtf(Vv[j][0] * Vv[j][0] + Vv[j][1] * Vv[j][1] + Vv[j][2] * Vv[j][2] + 1e-8f);
        cat[j * 256 + k] = sv[j];
        cat[j * 256 + 128 + k] = Vn;
    }
    __syncthreads();
    float a1[UPB];
    #pragma unroll
    for (int j = 0; j < UPB; ++j) a1[j] = b1[k];
    for (int h = 0; h < 256; h += 4) {
        float w0 = w1[h * 128 + k],       wv1 = w1[(h + 1) * 128 + k];
        float w2v = w1[(h + 2) * 128 + k], w3 = w1[(h + 3) * 128 + k];
        #pragma unroll
        for (int j = 0; j < UPB; ++j) {
            const float4 x = *reinterpret_cast<const float4*>(&cat[j * 256 + h]);
            a1[j] = fmaf(x.w, w3, fmaf(x.z, w2v, fmaf(x.y, wv1, fmaf(x.x, w0, a1[j]))));
        }
    }
    #pragma unroll
    for (int j = 0; j < UPB; ++j) a1l[j * 128 + k] = silu_f(a1[j]);   // disjoint from cat region
    __syncthreads();
    float a0[UPB], aH[UPB], a2[UPB];
    #pragma unroll
    for (int j = 0; j < UPB; ++j) { a0[j] = b2[k]; aH[j] = b2[128 + k]; a2[j] = b2[256 + k]; }
    for (int h = 0; h < 128; h += 4) {
        float wa0 = w2[h * 384 + k],       wa1 = w2[(h + 1) * 384 + k];
        float wa2 = w2[(h + 2) * 384 + k], wa3 = w2[(h + 3) * 384 + k];
        float wb0 = w2[h * 384 + 128 + k],       wb1 = w2[(h + 1) * 384 + 128 + k];
        float wb2 = w2[(h + 2) * 384 + 128 + k], wb3 = w2[(h + 3) * 384 + 128 + k];
        float wc0 = w2[h * 384 + 256 + k],       wc1 = w2[(h + 1) * 384 + 256 + k];
        float wc2 = w2[(h + 2) * 384 + 256 + k], wc3 = w2[(h + 3) * 384 + 256 + k];
        #pragma unroll
        for (int j = 0; j < UPB; ++j) {
            const float4 x = *reinterpret_cast<const float4*>(&a1l[j * 128 + h]);
            a0[j] = fmaf(x.w, wa3, fmaf(x.z, wa2, fmaf(x.y, wa1, fmaf(x.x, wa0, a0[j]))));
            aH[j] = fmaf(x.w, wb3, fmaf(x.z, wb2, fmaf(x.y, wb1, fmaf(x.x, wb0, aH[j]))));
            a2[j] = fmaf(x.w, wc3, fmaf(x.z, wc2, fmaf(x.y, wc1, fmaf(x.x, wc0, a2[j]))));
        }
    }
    #pragma unroll
    for (int j = 0; j < UPB; ++j) {
        int n = n0 + j;
        if (n < N_) {
            size_t vo = (size_t)n * 384;
            float dot = 0.0f;
            #pragma unroll
            for (int c = 0; c < 3; ++c) {
                float nv = vnk[j][c] + a0[j] * Uv[j][c];
                v[vo + c * 128 + k] = nv;
                dot += Uv[j][c] * Vv[j][c];
            }
            s[(size_t)n * 128 + k] = sv[j] + aH[j] * dot + a2[j];
        }
    }
}

// output heads: 8 nodes per block
#define HPB 8
__global__ __launch_bounds__(128, 4) void heads_kernel(
    const float* __restrict__ s,
    const float* __restrict__ hc_w1, const float* __restrict__ hc_b1,
    const float* __restrict__ hc_w2, const float* __restrict__ hc_b2,
    const float* __restrict__ ht_w1, const float* __restrict__ ht_b1,
    const float* __restrict__ ht_w2, const float* __restrict__ ht_b2,
    float* __restrict__ outc, float* __restrict__ outt, int N_) {
    int n0 = blockIdx.x * HPB;
    int k = threadIdx.x;
    __shared__ float sr[HPB][128];
    __shared__ float h1[HPB][128];
    __shared__ float h2[HPB][128];
    #pragma unroll
    for (int j = 0; j < HPB; ++j) {
        int n = n0 + j;
        if (n < N_) sr[j][k] = s[(size_t)n * 128 + k];
        else sr[j][k] = 0.0f;
    }
    __syncthreads();
    float a[HPB], b[HPB];
    #pragma unroll
    for (int j = 0; j < HPB; ++j) { a[j] = hc_b1[k]; b[j] = ht_b1[k]; }
    for (int h = 0; h < 128; h += 4) {
        float wa0 = hc_w1[h * 128 + k],       wa1 = hc_w1[(h + 1) * 128 + k];
        float wa2 = hc_w1[(h + 2) * 128 + k], wa3 = hc_w1[(h + 3) * 128 + k];
        float wb0 = ht_w1[h * 128 + k],       wb1 = ht_w1[(h + 1) * 128 + k];
        float wb2 = ht_w1[(h + 2) * 128 + k], wb3 = ht_w1[(h + 3) * 128 + k];
        #pragma unroll
        for (int j = 0; j < HPB; ++j) {
            const float4 x = *reinterpret_cast<const float4*>(&sr[j][h]);
            a[j] = fmaf(x.w, wa3, fmaf(x.z, wa2, fmaf(x.y, wa1, fmaf(x.x, wa0, a[j]))));
            b[j] = fmaf(x.w, wb3, fmaf(x.z, wb2, fmaf(x.y, wb1, fmaf(x.x, wb0, b[j]))));
        }
    }
    #pragma unroll
    for (int j = 0; j < HPB; ++j) {
        h1[j][k] = silu_f(a[j]);
        h2[j][k] = silu_f(b[j]);
    }
    __syncthreads();
    if (k < 101) {
        for (int j = 0; j < HPB; ++j) {
            int n = n0 + j;
            if (n >= N_) break;
            float c = ht_b2[k];
            #pragma unroll 4
            for (int h = 0; h < 128; ++h) c += h2[j][h] * ht_w2[h * 101 + k];
            outt[(size_t)n * 101 + k] = c;
        }
    }
    if (k < 3) {
        for (int j = 0; j < HPB; ++j) {
            int n = n0 + j;
            if (n >= N_) break;
            float c = hc_b2[k];
            #pragma unroll 4
            for (int h = 0; h < 128; ++h) c += h1[j][h] * hc_w2[h * 3 + k];
            outc[(size_t)n * 3 + k] = c;
        }
    }
}

extern "C" void kernel_launch(void* const* d_in, const int* in_sizes, int n_in,
                              void* d_out, int out_size, void* d_ws, size_t ws_size,
                              hipStream_t stream) {
    const float* coords  = (const float*)d_in[0];
    const int*   types   = (const int*)d_in[1];
    const float* z       = (const float*)d_in[2];
    const float* t       = (const float*)d_in[3];
    const int*   eidx    = (const int*)d_in[4];
    const int*   batch   = (const int*)d_in[5];
    const float* lattice = (const float*)d_in[6];
    const float* offs    = (const float*)d_in[7];
    const float* aemb    = (const float*)d_in[8];
    const float* z_w     = (const float*)d_in[9];
    const float* z_b     = (const float*)d_in[10];
    const float* t_w     = (const float*)d_in[11];
    const float* t_b     = (const float*)d_in[12];
    const float* msg_w1  = (const float*)d_in[13];
    const float* msg_b1  = (const float*)d_in[14];
    const float* msg_w2  = (const float*)d_in[15];
    const float* msg_b2  = (const float*)d_in[16];
    const float* rbf_w   = (const float*)d_in[17];
    const float* rbf_b   = (const float*)d_in[18];
    const float* Um      = (const float*)d_in[19];
    const float* Vm      = (const float*)d_in[20];
    const float* upd_w1  = (const float*)d_in[21];
    const float* upd_b1  = (const float*)d_in[22];
    const float* upd_w2  = (const float*)d_in[23];
    const float* upd_b2  = (const float*)d_in[24];
    const float* hc_w1   = (const float*)d_in[25];
    const float* hc_b1   = (const float*)d_in[26];
    const float* hc_w2   = (const float*)d_in[27];
    const float* hc_b2   = (const float*)d_in[28];
    const float* ht_w1   = (const float*)d_in[29];
    const float* ht_b1   = (const float*)d_in[30];
    const float* ht_w2   = (const float*)d_in[31];
    const float* ht_b2   = (const float*)d_in[32];

    const int N = in_sizes[1];
    const int G = in_sizes[3];
    const int E = in_sizes[4] / 2;
    const int* srcI = eidx;
    const int* dstI = eidx + E;

    char* ws = (char*)d_ws;
    auto alloc = [&](size_t bytes) {
        char* p = ws;
        ws += (bytes + 255) & ~(size_t)255;
        return p;
    };
    float* s_buf   = (float*)alloc((size_t)N * HD * 4);
    float* v_buf   = (float*)alloc((size_t)N * H3 * 4);
    float* dv_buf  = (float*)alloc((size_t)N * H3 * 4);
    float* phi_buf = (float*)alloc((size_t)N * H3 * 4);
    float* condG   = (float*)alloc((size_t)G * HD * 4);
    float* dist_s  = (float*)alloc((size_t)E * 4);
    float* unit_s  = (float*)alloc((size_t)E * 3 * 4);
    int*   src_s   = (int*)alloc((size_t)E * 4);
    int*   dst_s   = (int*)alloc((size_t)E * 4);
    int*   cur     = (int*)alloc((size_t)N * 4);
    // temporaries (original-order geometry) aliased into phi_buf (not yet live)
    float* dist_t  = phi_buf;                 // E floats
    float* unit_t  = phi_buf + E;             // 3E floats   (4E*4 = 2.56 MB << 30.7 MB)

    hipMemsetAsync(v_buf, 0, (size_t)N * H3 * 4, stream);
    hipMemsetAsync(cur, 0, (size_t)N * 4, stream);
    init_kernel<<<(N * HD + 255) / 256, 256, 0, stream>>>(types, aemb, s_buf, N);
    cond_kernel<<<G, 128, 0, stream>>>(z, t, z_w, z_b, t_w, t_b, condG);
    geom_kernel<<<(E + 255) / 256, 256, 0, stream>>>(coords, srcI, dstI, batch, lattice, offs, dist_t, unit_t, E);
    // counting sort by dst (reused across all 4 layers)
    hist_kernel<<<(E + 255) / 256, 256, 0, stream>>>(dstI, cur, E);
    {
        int* cnt2 = (int*)(phi_buf + 4 * (size_t)E);  // after dist_t/unit_t region
        hipMemcpyAsync(cnt2, cur, (size_t)N * 4, hipMemcpyDeviceToDevice, stream);
        scan_kernel<<<1, 1024, 0, stream>>>(cnt2, cur, N);
    }
    scatter_kernel<<<(E + 255) / 256, 256, 0, stream>>>(srcI, dstI, dist_t, unit_t, cur,
                                                        dist_s, unit_s, src_s, dst_s, E);

    int nblocksP = (N + NPB - 1) / NPB;
    int nblocksU = (N + UPB - 1) / UPB;
    int nblocksH = (N + HPB - 1) / HPB;
    int eblocks = (E + EPB - 1) / EPB;
    for (int l = 0; l < 4; ++l) {
        phi_kernel<<<nblocksP, 128, 0, stream>>>(s_buf, condG, batch,
                                          msg_w1 + (size_t)l * HD * HD, msg_b1 + (size_t)l * HD,
                                          msg_w2 + (size_t)l * HD * H3, msg_b2 + (size_t)l * H3,
                                          phi_buf, N);
        hipMemsetAsync(dv_buf, 0, (size_t)N * H3 * 4, stream);
        edge_kernel<<<eblocks, 512, 0, stream>>>(phi_buf, v_buf, dist_s, unit_s, src_s, dst_s,
                                                 rbf_w + (size_t)l * RD * H3, rbf_b + (size_t)l * H3,
                                                 s_buf, dv_buf, E);
        update_kernel<<<nblocksU, 128, 0, stream>>>(Um + (size_t)l * HD * HD, Vm + (size_t)l * HD * HD,
                                             upd_w1 + (size_t)l * 2 * HD * HD, upd_b1 + (size_t)l * HD,
                                             upd_w2 + (size_t)l * HD * H3, upd_b2 + (size_t)l * H3,
                                             s_buf, v_buf, dv_buf, N);
    }
    heads_kernel<<<nblocksH, 128, 0, stream>>>(s_buf, hc_w1, hc_b1, hc_w2, hc_b2,
                                        ht_w1, ht_b1, ht_w2, ht_b2,
                                        (float*)d_out, (float*)d_out + (size_t)N * 3, N);
}